// Round 5
// baseline (736.924 us; speedup 1.0000x reference)
//
#include <hip/hip_runtime.h>
#include <hip/hip_bf16.h>

#define NSITES 100000
#define KOFFS 27
#define CIN 64
#define COUT 128
#define NROWS1 (NSITES + 1)   // table rows incl zero sentinel row

typedef unsigned short u16;
typedef __attribute__((ext_vector_type(8))) short s16x8;
typedef __attribute__((ext_vector_type(4))) float f32x4;
typedef __attribute__((ext_vector_type(16))) float f32x16;

static __device__ __forceinline__ u16 f2bf(float f) {
    union { float f; unsigned u; } x; x.f = f;
    return (u16)((x.u + 0x7FFFu + ((x.u >> 16) & 1u)) >> 16);
}
static __device__ __forceinline__ float bf2f(u16 v) {
    union { unsigned u; float f; } x; x.u = ((unsigned)v) << 16;
    return x.f;
}

// Barrier with LDS-visibility only: drains ds-writes (lgkmcnt), leaves global
// loads (gather/B prefetch) in flight. __syncthreads would drain vmcnt(0).
static __device__ __forceinline__ void lds_barrier() {
    asm volatile("s_waitcnt lgkmcnt(0)" ::: "memory");
    __builtin_amdgcn_s_barrier();
    __builtin_amdgcn_sched_barrier(0);
}

// ---------- prep: transpose/convert weights to bf16 [k][d][c], zero stat partials ----------
__global__ void prep_kernel(const float* __restrict__ W1, const float* __restrict__ W2,
                            const float* __restrict__ Wsk,
                            u16* __restrict__ W1t, u16* __restrict__ W2t,
                            u16* __restrict__ Wskt, float* __restrict__ zero_area) {
    int i = blockIdx.x * 256 + threadIdx.x;
    if (i < 27 * 64 * 128) {
        int k = i / 8192, r = i & 8191, d = r >> 6, c = r & 63;
        W1t[i] = f2bf(W1[k * 8192 + c * 128 + d]);
        return;
    }
    i -= 27 * 64 * 128;
    if (i < 27 * 128 * 128) {
        int k = i / 16384, r = i & 16383, d = r >> 7, c = r & 127;
        W2t[i] = f2bf(W2[k * 16384 + c * 128 + d]);
        return;
    }
    i -= 27 * 128 * 128;
    if (i < 8192) {
        int d = i >> 6, c = i & 63;
        Wskt[i] = f2bf(Wsk[c * 128 + d]);
        return;
    }
    i -= 8192;
    zero_area[i] = 0.0f;  // 4 * 64*128 partial-stat floats
}

// ---------- x (fp32) -> bf16 SLICED table [4][N+1][16], zero sentinel row ----------
__global__ void convert_x_kernel(const float* __restrict__ x, u16* __restrict__ xb) {
    long long e = ((long long)blockIdx.x * 256 + threadIdx.x) * 8;
    if (e >= (long long)NROWS1 * CIN) return;
    int row = (int)(e >> 6);
    int col = (int)(e & 63);
    s16x8 o;
    if (row < NSITES) {
        float4 v0 = *(const float4*)(x + e);
        float4 v1 = *(const float4*)(x + e + 4);
        o[0] = (short)f2bf(v0.x); o[1] = (short)f2bf(v0.y);
        o[2] = (short)f2bf(v0.z); o[3] = (short)f2bf(v0.w);
        o[4] = (short)f2bf(v1.x); o[5] = (short)f2bf(v1.y);
        o[6] = (short)f2bf(v1.z); o[7] = (short)f2bf(v1.w);
    } else {
#pragma unroll
        for (int j = 0; j < 8; ++j) o[j] = 0;
    }
    // slice = col/16; col is 8-aligned so the 8 elems stay inside one slice
    *(s16x8*)(xb + ((size_t)(col >> 4) * NROWS1 + row) * 16 + (col & 15)) = o;
}

// ---------- gather-GEMM conv: K-sliced passes, L2-resident 3.2MB slices ----------
// y[n0+r, :] = sum_k xin[nbr[r,k]] @ Wt[k]^T, xin sliced [NSL][N+1][16] bf16.
// s-pass outer (slice resident in each XCD L2), k inner, acc in registers.
// MFMA 32x32x16 (K=16 == slice width). Block: 256 thr = 4 waves, 64-row tile;
// wave w owns cols [32w,32w+32): acc = 2 row-tiles x f32x16.
// Iteration = (s, group-of-4 k-offsets); 27 = 6*4+3 -> 7 groups/pass.
// Pipeline (round-3 invariant, unchanged): B two iters early, gathers three
// early, every B-issue precedes the next G-issue; lgkm-only barriers.
template <int NSL, bool IDENT_FUSE, bool STATS>
__global__ __launch_bounds__(256, 4) void conv_kernel(
    const u16* __restrict__ xin, const int* __restrict__ nbr,
    const u16* __restrict__ Wt, u16* __restrict__ yout,
    float* __restrict__ psum, float* __restrict__ psq,
    const u16* __restrict__ Wskt, float* __restrict__ outid) {
    constexpr int CK = NSL * 16;
    constexpr int NIT = NSL * 7;        // even (NSL = 4 or 8)
    constexpr int USTRIDE = 24;         // u16/row slot: 32B data + 16B pad (2-way banks)
    constexpr int UNIT = 64 * USTRIDE;  // one k-unit subtile
    constexpr int BUF = 4 * UNIT;
    __shared__ __align__(16) u16 a_tile[2 * BUF];
    __shared__ int nbr_tile[64 * KOFFS];

    const int tid = threadIdx.x;
    const int wave = tid >> 6;
    const int lane = tid & 63;
    const int l31 = lane & 31;
    const int hi = lane >> 5;
    const int n0 = blockIdx.x * 64;
    const int wc = wave * 32;
    const int su = tid >> 6;    // staging unit (0..3)
    const int srow = tid & 63;  // staging row

    for (int i = tid; i < 64 * KOFFS; i += 256) {
        int r = i / KOFFS;
        int kk = i - r * KOFFS;
        int row = n0 + r;
        nbr_tile[i] = (row < NSITES) ? nbr[row * KOFFS + kk] : NSITES;
    }
    __syncthreads();  // nbr_tile ready; clean vmcnt slate

    f32x16 acc0, acc1;
#pragma unroll
    for (int j = 0; j < 16; ++j) { acc0[j] = 0.0f; acc1[j] = 0.0f; }

    s16x8 gA[2], gB[2];      // gather sets: one row-slice (32B) per thread
    s16x8 bA[4], bB[4];      // B fragments: one per k-unit

    auto gload = [&](s16x8 (&g)[2], int dit) {
        int grp = dit % 7, s = dit / 7;
        int gsz = (grp == 6) ? 3 : 4;
        if (su < gsz) {
            int k = grp * 4 + su;
            const u16* base = xin + ((size_t)s * NROWS1 +
                                     (size_t)nbr_tile[srow * KOFFS + k]) * 16;
            g[0] = *(const s16x8*)(base);
            g[1] = *(const s16x8*)(base + 8);
        }
    };
    auto bload = [&](s16x8 (&b)[4], int dit) {
        int grp = dit % 7, s = dit / 7;
        int gsz = (grp == 6) ? 3 : 4;
        const u16* wb = Wt + (size_t)(wc + l31) * CK + s * 16 + hi * 8;
#pragma unroll
        for (int u = 0; u < 4; ++u)
            if (u < gsz) b[u] = *(const s16x8*)(wb + (size_t)(grp * 4 + u) * COUT * CK);
    };
    auto awrite = [&](s16x8 (&g)[2], int dit) {
        int grp = dit % 7;
        int gsz = (grp == 6) ? 3 : 4;
        if (su < gsz) {
            u16* d = a_tile + (dit & 1) * BUF + su * UNIT + srow * USTRIDE;
            *(s16x8*)(d) = g[0];
            *(s16x8*)(d + 8) = g[1];
        }
    };
    auto domfma = [&](int it, s16x8 (&b)[4]) {
        int grp = it % 7;
        int gsz = (grp == 6) ? 3 : 4;
        const u16* base = a_tile + (it & 1) * BUF + l31 * USTRIDE + hi * 8;
        __builtin_amdgcn_s_setprio(1);
#pragma unroll
        for (int u = 0; u < 4; ++u) {
            if (u < gsz) {
                s16x8 a0 = *(const s16x8*)(base + u * UNIT);
                s16x8 a1 = *(const s16x8*)(base + u * UNIT + 32 * USTRIDE);
                acc0 = __builtin_amdgcn_mfma_f32_32x32x16_bf16(a0, b[u], acc0, 0, 0, 0);
                acc1 = __builtin_amdgcn_mfma_f32_32x32x16_bf16(a1, b[u], acc1, 0, 0, 0);
            }
        }
        __builtin_amdgcn_s_setprio(0);
    };

    // prologue — ordering invariant: each B_j issued before G_{j+1}
    gload(gA, 0); bload(bA, 0);
    awrite(gA, 0); gload(gA, 1); bload(bB, 1); gload(gB, 2);
    lds_barrier();  // buf0 visible

    for (int it = 0; it + 4 < NIT; it += 2) {
        awrite(gA, it + 1); gload(gA, it + 3); lds_barrier();
        domfma(it, bA); bload(bA, it + 2); lds_barrier();
        awrite(gB, it + 2); gload(gB, it + 4); lds_barrier();
        domfma(it + 1, bB); bload(bB, it + 3); lds_barrier();
    }
    // peeled tail: it = NIT-4 .. NIT-1 (compile-time guards)
    awrite(gA, NIT - 3); gload(gA, NIT - 1); lds_barrier();
    domfma(NIT - 4, bA); bload(bA, NIT - 2); lds_barrier();
    awrite(gB, NIT - 2); lds_barrier();
    domfma(NIT - 3, bB); bload(bB, NIT - 1); lds_barrier();
    awrite(gA, NIT - 1); lds_barrier();
    domfma(NIT - 2, bA); lds_barrier();
    domfma(NIT - 1, bB);

    // Store y row-major: C/D col=lane&31, row=(j&3)+8*(j>>2)+4*(lane>>5)  [m74/m101]
    const int colg = wc + l31;
#pragma unroll
    for (int j = 0; j < 16; ++j) {
        int rw = (j & 3) + 8 * (j >> 2) + 4 * hi;
        int r0 = n0 + rw;
        int r1 = n0 + 32 + rw;
        if (r0 < NSITES) yout[(size_t)r0 * COUT + colg] = f2bf(acc0[j]);
        if (r1 < NSITES) yout[(size_t)r1 * COUT + colg] = f2bf(acc1[j]);
    }

    if (STATS) {
        float s = 0.f, ss = 0.f;
#pragma unroll
        for (int j = 0; j < 16; ++j) {
            float v0 = acc0[j], v1 = acc1[j];
            s += v0 + v1; ss += v0 * v0 + v1 * v1;
        }
        s += __shfl_xor(s, 32); ss += __shfl_xor(ss, 32);
        if (lane < 32) {
            int slot = blockIdx.x & 63;
            atomicAdd(psum + slot * COUT + colg, s);
            atomicAdd(psq + slot * COUT + colg, ss);
        }
    }

    if (IDENT_FUSE) {
        // identity = x @ W_skip for the same 64 rows (sequential, sliced xb)
        {
            int grow = n0 + srow;
            size_t idx = (grow < NSITES) ? (size_t)grow : (size_t)NSITES;
            const u16* base = xin + ((size_t)su * NROWS1 + idx) * 16;
            s16x8 v0 = *(const s16x8*)(base);
            s16x8 v1 = *(const s16x8*)(base + 8);
            u16* d = a_tile + su * UNIT + srow * USTRIDE;  // buf0 free after tail
            *(s16x8*)(d) = v0;
            *(s16x8*)(d + 8) = v1;
        }
        lds_barrier();
#pragma unroll
        for (int j = 0; j < 16; ++j) { acc0[j] = 0.0f; acc1[j] = 0.0f; }
        s16x8 bsk[4];
        const u16* wb = Wskt + (size_t)(wc + l31) * CIN + hi * 8;
#pragma unroll
        for (int u = 0; u < 4; ++u) bsk[u] = *(const s16x8*)(wb + u * 16);
        const u16* base = a_tile + l31 * USTRIDE + hi * 8;
#pragma unroll
        for (int u = 0; u < 4; ++u) {
            s16x8 a0 = *(const s16x8*)(base + u * UNIT);
            s16x8 a1 = *(const s16x8*)(base + u * UNIT + 32 * USTRIDE);
            acc0 = __builtin_amdgcn_mfma_f32_32x32x16_bf16(a0, bsk[u], acc0, 0, 0, 0);
            acc1 = __builtin_amdgcn_mfma_f32_32x32x16_bf16(a1, bsk[u], acc1, 0, 0, 0);
        }
#pragma unroll
        for (int j = 0; j < 16; ++j) {
            int rw = (j & 3) + 8 * (j >> 2) + 4 * hi;
            int r0 = n0 + rw;
            int r1 = n0 + 32 + rw;
            if (r0 < NSITES) outid[(size_t)r0 * COUT + colg] = acc0[j];
            if (r1 < NSITES) outid[(size_t)r1 * COUT + colg] = acc1[j];
        }
    }
}

// ---------- reduce 64 slots -> per-column affine (a = gamma*rsqrt(var+eps), b = beta - mu*a) ----------
__global__ void bn_stats_kernel(const float* __restrict__ psum, const float* __restrict__ psq,
                                const float* __restrict__ gamma, const float* __restrict__ beta,
                                float* __restrict__ ab) {
    int col = threadIdx.x;  // 128 threads
    float s = 0.f, ss = 0.f;
    for (int i = 0; i < 64; ++i) { s += psum[i * COUT + col]; ss += psq[i * COUT + col]; }
    const float inv_n = 1.0f / (float)NSITES;
    float mu = s * inv_n;
    float var = ss * inv_n - mu * mu;
    float rs = rsqrtf(var + 1e-5f);
    float a = gamma[col] * rs;
    ab[col] = a;
    ab[COUT + col] = beta[col] - mu * a;
}

// ---------- h = bf16(relu(y*a+b)) into SLICED table [8][N+1][16], zero sentinel ----------
__global__ void bn_apply_kernel(const u16* __restrict__ y, const float* __restrict__ ab,
                                u16* __restrict__ h) {
    long long e = ((long long)blockIdx.x * 256 + threadIdx.x) * 8;
    if (e >= (long long)NROWS1 * COUT) return;
    int row = (int)(e >> 7);
    int col = (int)(e & 127);
    s16x8 o;
    if (row < NSITES) {
        s16x8 v = *(const s16x8*)(y + e);
#pragma unroll
        for (int j = 0; j < 8; ++j) {
            float r = bf2f((u16)v[j]) * ab[col + j] + ab[COUT + col + j];
            o[j] = (short)f2bf(fmaxf(r, 0.f));
        }
    } else {
#pragma unroll
        for (int j = 0; j < 8; ++j) o[j] = 0;
    }
    *(s16x8*)(h + ((size_t)(col >> 4) * NROWS1 + row) * 16 + (col & 15)) = o;
}

// ---------- out = relu(y2*a+b) + identity (identity resident in d_out); y2 is bf16 ----------
__global__ void final_kernel(const u16* __restrict__ y, const float* __restrict__ ab,
                             float* __restrict__ out) {
    long long e = ((long long)blockIdx.x * 256 + threadIdx.x) * 8;
    if (e >= (long long)NSITES * COUT) return;
    int cb = (int)(e & (COUT - 1));
    s16x8 v = *(const s16x8*)(y + e);
    float4 i0 = *(const float4*)(out + e);
    float4 i1 = *(const float4*)(out + e + 4);
    float is[8] = {i0.x, i0.y, i0.z, i0.w, i1.x, i1.y, i1.z, i1.w};
    float os[8];
#pragma unroll
    for (int j = 0; j < 8; ++j) {
        float r = bf2f((u16)v[j]) * ab[cb + j] + ab[COUT + cb + j];
        os[j] = fmaxf(r, 0.f) + is[j];
    }
    *(float4*)(out + e) = make_float4(os[0], os[1], os[2], os[3]);
    *(float4*)(out + e + 4) = make_float4(os[4], os[5], os[6], os[7]);
}

extern "C" void kernel_launch(void* const* d_in, const int* in_sizes, int n_in,
                              void* d_out, int out_size, void* d_ws, size_t ws_size,
                              hipStream_t stream) {
    const float* x   = (const float*)d_in[0];
    const int*   nbr = (const int*)d_in[1];
    const float* W1  = (const float*)d_in[2];
    const float* g1  = (const float*)d_in[3];
    const float* b1  = (const float*)d_in[4];
    const float* W2  = (const float*)d_in[5];
    const float* g2  = (const float*)d_in[6];
    const float* b2  = (const float*)d_in[7];
    const float* Wsk = (const float*)d_in[8];
    float* out = (float*)d_out;

    // workspace layout (bytes, 16B-aligned); total ~66 MB
    char* ws = (char*)d_ws;
    u16*   xb   = (u16*)(ws);                    // sliced [4][N+1][16]  = 12,800,128 B
    u16*   W1t  = (u16*)(ws + 12800128);         // 27*128*64 bf16       =    442,368 B
    u16*   W2t  = (u16*)(ws + 13242496);         // 27*128*128 bf16      =    884,736 B
    u16*   Wskt = (u16*)(ws + 14127232);         // 128*64 bf16          =     16,384 B
    u16*   y    = (u16*)(ws + 14143616);         // [N][128] bf16        = 25,600,000 B
    u16*   h1   = (u16*)(ws + 39743616);         // sliced [8][N+1][16]  = 25,600,256 B
    float* ps1  = (float*)(ws + 65343872);       // 4 * 64*128 f32 partials
    float* pq1  = ps1 + 8192;
    float* ps2  = pq1 + 8192;
    float* pq2  = ps2 + 8192;
    float* ab1  = pq2 + 8192;                    // 2*2*128 f32 affine params
    float* ab2  = ab1 + 256;

    const int NBLK = (NSITES + 63) / 64;  // 1563

    prep_kernel<<<2752, 256, 0, stream>>>(W1, W2, Wsk, W1t, W2t, Wskt, ps1);
    convert_x_kernel<<<3126, 256, 0, stream>>>(x, xb);
    // conv1 (4 slice-passes) + fused stats + fused identity (identity -> d_out)
    conv_kernel<4, true, true><<<NBLK, 256, 0, stream>>>(xb, nbr, W1t, y, ps1, pq1, Wskt, out);
    bn_stats_kernel<<<1, 128, 0, stream>>>(ps1, pq1, g1, b1, ab1);
    bn_apply_kernel<<<6251, 256, 0, stream>>>(y, ab1, h1);
    // conv2 (8 slice-passes) + fused stats
    conv_kernel<8, false, true><<<NBLK, 256, 0, stream>>>(h1, nbr, W2t, y, ps2, pq2, nullptr, nullptr);
    bn_stats_kernel<<<1, 128, 0, stream>>>(ps2, pq2, g2, b2, ab2);
    final_kernel<<<6250, 256, 0, stream>>>(y, ab2, out);
}

// Round 6
// 559.534 us; speedup vs baseline: 1.3170x; 1.3170x over previous
//
#include <hip/hip_runtime.h>
#include <hip/hip_bf16.h>

#define NSITES 100000
#define KOFFS 27
#define CIN 64
#define COUT 128

typedef unsigned short u16;
typedef __attribute__((ext_vector_type(8))) short s16x8;
typedef __attribute__((ext_vector_type(4))) float f32x4;

static __device__ __forceinline__ u16 f2bf(float f) {
    union { float f; unsigned u; } x; x.f = f;
    return (u16)((x.u + 0x7FFFu + ((x.u >> 16) & 1u)) >> 16);
}
static __device__ __forceinline__ float bf2f(u16 v) {
    union { unsigned u; float f; } x; x.u = ((unsigned)v) << 16;
    return x.f;
}

// Barrier with LDS-visibility only: drains ds-writes (lgkmcnt), leaves global
// loads (gather/B prefetch) in flight. __syncthreads would drain vmcnt(0).
static __device__ __forceinline__ void lds_barrier() {
    asm volatile("s_waitcnt lgkmcnt(0)" ::: "memory");
    __builtin_amdgcn_s_barrier();
    __builtin_amdgcn_sched_barrier(0);  // no hoisting of LDS ops across the barrier
}

// ---------- prep: transpose/convert weights to bf16 [k][d][c], zero stat partials ----------
__global__ void prep_kernel(const float* __restrict__ W1, const float* __restrict__ W2,
                            const float* __restrict__ Wsk,
                            u16* __restrict__ W1t, u16* __restrict__ W2t,
                            u16* __restrict__ Wskt, float* __restrict__ zero_area) {
    int i = blockIdx.x * 256 + threadIdx.x;
    if (i < 27 * 64 * 128) {
        int k = i / 8192, r = i & 8191, d = r >> 6, c = r & 63;
        W1t[i] = f2bf(W1[k * 8192 + c * 128 + d]);
        return;
    }
    i -= 27 * 64 * 128;
    if (i < 27 * 128 * 128) {
        int k = i / 16384, r = i & 16383, d = r >> 7, c = r & 127;
        W2t[i] = f2bf(W2[k * 16384 + c * 128 + d]);
        return;
    }
    i -= 27 * 128 * 128;
    if (i < 8192) {
        int d = i >> 6, c = i & 63;
        Wskt[i] = f2bf(Wsk[c * 128 + d]);
        return;
    }
    i -= 8192;
    zero_area[i] = 0.0f;  // 4 * 64*128 partial-stat floats
}

// ---------- x (fp32) -> bf16 rows, plus zero sentinel row N ----------
__global__ void convert_x_kernel(const float* __restrict__ x, u16* __restrict__ xb) {
    long long e = ((long long)blockIdx.x * 256 + threadIdx.x) * 8;
    if (e >= (long long)(NSITES + 1) * CIN) return;
    s16x8 o;
    if (e < (long long)NSITES * CIN) {
        float4 v0 = *(const float4*)(x + e);
        float4 v1 = *(const float4*)(x + e + 4);
        o[0] = (short)f2bf(v0.x); o[1] = (short)f2bf(v0.y);
        o[2] = (short)f2bf(v0.z); o[3] = (short)f2bf(v0.w);
        o[4] = (short)f2bf(v1.x); o[5] = (short)f2bf(v1.y);
        o[6] = (short)f2bf(v1.z); o[7] = (short)f2bf(v1.w);
    } else {
#pragma unroll
        for (int j = 0; j < 8; ++j) o[j] = 0;
    }
    *(s16x8*)(xb + e) = o;
}

// ---------- gather-GEMM conv: 1-barrier/iter pipeline, max resident waves ----------
// y[n0+r, :] = sum_k xin[nbr[r,k]] @ Wt[k]^T ; Wt layout [27][COUT][CK] bf16.
// Block: 256 thr = 4 waves, 64-row tile; wave w owns output cols [32w, 32w+32).
// Service-rate model (rounds 0-5): the gather miss path is queue-saturated;
// throughput scales with concurrent demand. So: one barrier and ONE vm-wait
// point per iteration, and occupancy pushed to 4 (conv2) / 6 (conv1) blocks/CU.
// Iteration k:  mfma(buf[k&1], B_k)   <- its vmcnt wait (<=B_k) also drains G_{k+1}
//               awrite(A_{k+1} -> buf[(k+1)&1])   <- no extra wait needed
//               bload(B_{k+2}); gload(G_{k+3})    <- B before G: ordering invariant
//               lds_barrier()
// Single trailing barrier covers RAW (awrite_k -> mfma_{k+1}) and WAR
// (mfma_k -> awrite_{k+1}) since the two buffers alternate.
template <int CK, bool IDENT_FUSE, bool STATS>
__global__ __launch_bounds__(256, 4) void conv_kernel(
    const u16* __restrict__ xin, const int* __restrict__ nbr,
    const u16* __restrict__ Wt, u16* __restrict__ yout,
    float* __restrict__ psum, float* __restrict__ psq, int nk_unused,
    const u16* __restrict__ Wskt, float* __restrict__ outid) {
    constexpr int STRIDE = CK + 4;   // +4 bf16 pad (round-1/3 conflict level)
    constexpr int KSTEPS = CK / 32;
    constexpr int CPR = CK / 8;      // 16B chunks per row
    constexpr int RPP = 256 / CPR;   // rows staged per pass
    constexpr int NPASS = 64 / RPP;
    __shared__ __align__(16) u16 a_tile[2][64 * STRIDE];
    __shared__ int nbr_tile[64 * KOFFS];

    const int tid = threadIdx.x;
    const int wave = tid >> 6;
    const int lane = tid & 63;
    const int m = lane & 15;
    const int q = lane >> 4;
    const int n0 = blockIdx.x * 64;
    const int wc = wave * 32;
    const int srow = tid / CPR;
    const int schunk = tid % CPR;

    for (int i = tid; i < 64 * KOFFS; i += 256) {
        int r = i / KOFFS;
        int kk = i - r * KOFFS;
        int row = n0 + r;
        nbr_tile[i] = (row < NSITES) ? nbr[row * KOFFS + kk] : NSITES;
    }
    __syncthreads();  // nbr_tile ready; clean vmcnt slate

    f32x4 acc[4][2];
#pragma unroll
    for (int rt = 0; rt < 4; ++rt)
#pragma unroll
        for (int ct = 0; ct < 2; ++ct)
#pragma unroll
            for (int r = 0; r < 4; ++r) acc[rt][ct][r] = 0.0f;

    s16x8 gA[NPASS], gB[NPASS];          // gather register sets (A-rows)
    s16x8 bA[2][KSTEPS], bB[2][KSTEPS];  // B fragment sets

    auto gload = [&](s16x8 (&g)[NPASS], int kk) {
#pragma unroll
        for (int p = 0; p < NPASS; ++p) {
            int r = p * RPP + srow;
            g[p] = *(const s16x8*)(xin + (long long)nbr_tile[r * KOFFS + kk] * CK + schunk * 8);
        }
    };
    auto bload = [&](s16x8 (&b)[2][KSTEPS], int kk) {
        const u16* wb = Wt + (long long)kk * (COUT * CK);
#pragma unroll
        for (int ct = 0; ct < 2; ++ct)
#pragma unroll
            for (int ks = 0; ks < KSTEPS; ++ks)
                b[ct][ks] = *(const s16x8*)(wb + (wc + ct * 16 + m) * CK + ks * 32 + q * 8);
    };
    auto awrite = [&](s16x8 (&g)[NPASS], int buf) {
#pragma unroll
        for (int p = 0; p < NPASS; ++p)
            *(s16x8*)(&a_tile[buf][(p * RPP + srow) * STRIDE + schunk * 8]) = g[p];
    };
    auto mfma_from = [&](int buf, s16x8 (&b)[2][KSTEPS]) {
        __builtin_amdgcn_s_setprio(1);
#pragma unroll
        for (int ks = 0; ks < KSTEPS; ++ks) {
            s16x8 af[4];
#pragma unroll
            for (int rt = 0; rt < 4; ++rt)
                af[rt] = *(const s16x8*)(&a_tile[buf][(rt * 16 + m) * STRIDE + ks * 32 + q * 8]);
#pragma unroll
            for (int rt = 0; rt < 4; ++rt)
#pragma unroll
                for (int ct = 0; ct < 2; ++ct)
                    acc[rt][ct] = __builtin_amdgcn_mfma_f32_16x16x32_bf16(
                        af[rt], b[ct][ks], acc[rt][ct], 0, 0, 0);
        }
        __builtin_amdgcn_s_setprio(0);
    };

    // prologue — set/buffer assignment: awrite at iter k consumes the g-set
    // holding G_{k+1}: gB on even k, gA on odd k. B_j issued before G_{j+1}.
    gload(gA, 0);      // G_0
    bload(bA, 0);      // B_0
    awrite(gA, 0);     // stage A_0 into buf0 (waits only G_0)
    gload(gB, 1);      // G_1 (consumed at iter 0)
    bload(bB, 1);      // B_1
    gload(gA, 2);      // G_2 (consumed at iter 1)
    lds_barrier();     // buf0 visible

    // main loop, iters 0..23 as even/odd pairs (all prefetch indices <= 26)
    for (int k = 0; k < 24; k += 2) {
        // even iter k
        mfma_from(0, bA);          // waits <=B_k, draining G_{k+1}; keeps G_{k+2},G_{k+3}
        awrite(gB, 1);             // A_{k+1} -> buf1 (G_{k+1} already complete)
        bload(bA, k + 2);
        gload(gB, k + 3);
        lds_barrier();
        // odd iter k+1
        mfma_from(1, bB);
        awrite(gA, 0);             // A_{k+2} -> buf0
        bload(bB, k + 3);
        gload(gA, k + 4);
        lds_barrier();
    }
    // peeled tail: iters 24, 25, 26 (KOFFS = 27)
    mfma_from(0, bA);              // B_24
    awrite(gB, 1);                 // A_25
    bload(bA, 26);                 // B_26
    lds_barrier();
    mfma_from(1, bB);              // B_25
    awrite(gA, 0);                 // A_26
    lds_barrier();
    mfma_from(0, bA);              // B_26

    // Store y (bf16): C/D layout col=lane&15, row=(lane>>4)*4+reg  [m89-verified]
#pragma unroll
    for (int rt = 0; rt < 4; ++rt) {
        int rowb = n0 + rt * 16 + q * 4;
#pragma unroll
        for (int ct = 0; ct < 2; ++ct) {
            int col = wc + ct * 16 + m;
#pragma unroll
            for (int r = 0; r < 4; ++r) {
                int row = rowb + r;
                if (row < NSITES) yout[(long long)row * COUT + col] = f2bf(acc[rt][ct][r]);
            }
        }
    }

    if (STATS) {
#pragma unroll
        for (int ct = 0; ct < 2; ++ct) {
            float s = 0.f, ss = 0.f;
#pragma unroll
            for (int rt = 0; rt < 4; ++rt)
#pragma unroll
                for (int r = 0; r < 4; ++r) {
                    float v = acc[rt][ct][r];
                    s += v; ss += v * v;
                }
            s += __shfl_xor(s, 16); ss += __shfl_xor(ss, 16);
            s += __shfl_xor(s, 32); ss += __shfl_xor(ss, 32);
            if (q == 0) {
                int col = wc + ct * 16 + m;
                int slot = blockIdx.x & 63;  // 64-slot tree cuts atomic contention
                atomicAdd(psum + slot * COUT + col, s);
                atomicAdd(psq + slot * COUT + col, ss);
            }
        }
    }

    if (IDENT_FUSE) {
        // identity = x @ W_skip for the same 64 rows (no gather); reuses acc regs
        lds_barrier();  // last MFMA's reads of a_tile[0] done before restaging
#pragma unroll
        for (int rt = 0; rt < 4; ++rt)
#pragma unroll
            for (int ct = 0; ct < 2; ++ct)
#pragma unroll
                for (int r = 0; r < 4; ++r) acc[rt][ct][r] = 0.0f;
        s16x8 aid[NPASS];
#pragma unroll
        for (int p = 0; p < NPASS; ++p) {
            int row = n0 + p * RPP + srow;
            long long idx = (row < NSITES) ? row : NSITES;
            aid[p] = *(const s16x8*)(xin + idx * CK + schunk * 8);
        }
        s16x8 bfi[2][KSTEPS];
#pragma unroll
        for (int ct = 0; ct < 2; ++ct)
#pragma unroll
            for (int ks = 0; ks < KSTEPS; ++ks)
                bfi[ct][ks] = *(const s16x8*)(Wskt + (wc + ct * 16 + m) * CK + ks * 32 + q * 8);
        awrite(aid, 0);
        lds_barrier();
        mfma_from(0, bfi);
#pragma unroll
        for (int rt = 0; rt < 4; ++rt) {
            int rowb = n0 + rt * 16 + q * 4;
#pragma unroll
            for (int ct = 0; ct < 2; ++ct) {
                int col = wc + ct * 16 + m;
#pragma unroll
                for (int r = 0; r < 4; ++r) {
                    int row = rowb + r;
                    if (row < NSITES) outid[(long long)row * COUT + col] = acc[rt][ct][r];
                }
            }
        }
    }
}

// ---------- reduce 64 slots -> per-column affine (a = gamma*rsqrt(var+eps), b = beta - mu*a) ----------
__global__ void bn_stats_kernel(const float* __restrict__ psum, const float* __restrict__ psq,
                                const float* __restrict__ gamma, const float* __restrict__ beta,
                                float* __restrict__ ab) {
    int col = threadIdx.x;  // 128 threads
    float s = 0.f, ss = 0.f;
    for (int i = 0; i < 64; ++i) { s += psum[i * COUT + col]; ss += psq[i * COUT + col]; }
    const float inv_n = 1.0f / (float)NSITES;
    float mu = s * inv_n;
    float var = ss * inv_n - mu * mu;
    float rs = rsqrtf(var + 1e-5f);
    float a = gamma[col] * rs;
    ab[col] = a;
    ab[COUT + col] = beta[col] - mu * a;
}

// ---------- h = bf16(relu(y*a+b)), plus zero sentinel row; y is bf16 ----------
__global__ void bn_apply_kernel(const u16* __restrict__ y, const float* __restrict__ ab,
                                u16* __restrict__ h) {
    long long e = ((long long)blockIdx.x * 256 + threadIdx.x) * 8;
    if (e >= (long long)(NSITES + 1) * COUT) return;
    s16x8 o;
    if (e < (long long)NSITES * COUT) {
        int cb = (int)(e & (COUT - 1));
        s16x8 v = *(const s16x8*)(y + e);
#pragma unroll
        for (int j = 0; j < 8; ++j) {
            float r = bf2f((u16)v[j]) * ab[cb + j] + ab[COUT + cb + j];
            o[j] = (short)f2bf(fmaxf(r, 0.f));
        }
    } else {
#pragma unroll
        for (int j = 0; j < 8; ++j) o[j] = 0;
    }
    *(s16x8*)(h + e) = o;
}

// ---------- out = relu(y*a+b) + identity (identity resident in d_out); y is bf16 ----------
__global__ void final_kernel(const u16* __restrict__ y, const float* __restrict__ ab,
                             float* __restrict__ out) {
    long long e = ((long long)blockIdx.x * 256 + threadIdx.x) * 8;
    if (e >= (long long)NSITES * COUT) return;
    int cb = (int)(e & (COUT - 1));
    s16x8 v = *(const s16x8*)(y + e);
    float4 i0 = *(const float4*)(out + e);
    float4 i1 = *(const float4*)(out + e + 4);
    float is[8] = {i0.x, i0.y, i0.z, i0.w, i1.x, i1.y, i1.z, i1.w};
    float os[8];
#pragma unroll
    for (int j = 0; j < 8; ++j) {
        float r = bf2f((u16)v[j]) * ab[cb + j] + ab[COUT + cb + j];
        os[j] = fmaxf(r, 0.f) + is[j];
    }
    *(float4*)(out + e) = make_float4(os[0], os[1], os[2], os[3]);
    *(float4*)(out + e + 4) = make_float4(os[4], os[5], os[6], os[7]);
}

extern "C" void kernel_launch(void* const* d_in, const int* in_sizes, int n_in,
                              void* d_out, int out_size, void* d_ws, size_t ws_size,
                              hipStream_t stream) {
    const float* x   = (const float*)d_in[0];
    const int*   nbr = (const int*)d_in[1];
    const float* W1  = (const float*)d_in[2];
    const float* g1  = (const float*)d_in[3];
    const float* b1  = (const float*)d_in[4];
    const float* W2  = (const float*)d_in[5];
    const float* g2  = (const float*)d_in[6];
    const float* b2  = (const float*)d_in[7];
    const float* Wsk = (const float*)d_in[8];
    float* out = (float*)d_out;

    // workspace layout (bytes, 16B-aligned); total ~66 MB
    char* ws = (char*)d_ws;
    u16*   xb   = (u16*)(ws);                    // (N+1)*64 bf16      = 12,800,128 B
    u16*   W1t  = (u16*)(ws + 12800128);         // 27*128*64 bf16     =    442,368 B
    u16*   W2t  = (u16*)(ws + 13242496);         // 27*128*128 bf16    =    884,736 B
    u16*   Wskt = (u16*)(ws + 14127232);         // 128*64 bf16        =     16,384 B
    u16*   y    = (u16*)(ws + 14143616);         // N*128 bf16         = 25,600,000 B
    u16*   h1   = (u16*)(ws + 39743616);         // (N+1)*128 bf16     = 25,600,256 B
    float* ps1  = (float*)(ws + 65343872);       // 4 * 64*128 f32 partials
    float* pq1  = ps1 + 8192;
    float* ps2  = pq1 + 8192;
    float* pq2  = ps2 + 8192;
    float* ab1  = pq2 + 8192;                    // 2*2*128 f32 affine params
    float* ab2  = ab1 + 256;

    const int NBLK = (NSITES + 63) / 64;  // 1563

    prep_kernel<<<2752, 256, 0, stream>>>(W1, W2, Wsk, W1t, W2t, Wskt, ps1);
    convert_x_kernel<<<3126, 256, 0, stream>>>(x, xb);
    // conv1 + fused stats + fused identity (identity -> d_out)
    conv_kernel<64, true, true><<<NBLK, 256, 0, stream>>>(xb, nbr, W1t, y, ps1, pq1, KOFFS, Wskt, out);
    bn_stats_kernel<<<1, 128, 0, stream>>>(ps1, pq1, g1, b1, ab1);
    bn_apply_kernel<<<6251, 256, 0, stream>>>(y, ab1, h1);
    // conv2 + fused stats (reuses y buffer)
    conv_kernel<128, false, true><<<NBLK, 256, 0, stream>>>(h1, nbr, W2t, y, ps2, pq2, KOFFS, nullptr, nullptr);
    bn_stats_kernel<<<1, 128, 0, stream>>>(ps2, pq2, g2, b2, ab2);
    final_kernel<<<6250, 256, 0, stream>>>(y, ab2, out);
}